// Round 1
// baseline (417.482 us; speedup 1.0000x reference)
//
#include <hip/hip_runtime.h>
#include <stdint.h>

#define N_NODES 50000
#define N_EDGES 800000
#define CAP 64      // bin capacity for real (non-self) in-edges; Poisson(16) max over 50k ~44
#define NPART 8     // XCD count; blockIdx % 8 ~ XCD id (dispatch round-robin heuristic)
#define PARTSZ 6250 // N_NODES / NPART (exact)
#define SCAP 104448 // per-(layer,part) staging capacity; mean 100k, sigma ~300

// ---------- bf16 helpers ----------
__device__ __forceinline__ float b2f_bits(unsigned int lo16) {
    union { unsigned int i; float f; } v; v.i = lo16 << 16; return v.f;
}
__device__ __forceinline__ unsigned short f2b(float f) {
    union { float f; unsigned int i; } v; v.f = f;
    unsigned int x = v.i;
    return (unsigned short)((x + 0x7fffu + ((x >> 16) & 1u)) >> 16);
}
__device__ __forceinline__ void unpack8(const uint4 u, float* f) {
    f[0] = b2f_bits(u.x & 0xffffu); f[1] = b2f_bits(u.x >> 16);
    f[2] = b2f_bits(u.y & 0xffffu); f[3] = b2f_bits(u.y >> 16);
    f[4] = b2f_bits(u.z & 0xffffu); f[5] = b2f_bits(u.z >> 16);
    f[6] = b2f_bits(u.w & 0xffffu); f[7] = b2f_bits(u.w >> 16);
}

// ---------- GEMM: XL[n,F](bf16) = X[n,CIN](f32) @ W[CIN,F](f32) ----------
template<int CIN, int F, int FT, int NT>
__global__ __launch_bounds__(256) void gemm_kernel(
    const float* __restrict__ X,
    const float* __restrict__ W,
    unsigned short* __restrict__ XL, int n)
{
    __shared__ float wlds[CIN * FT];
    constexpr int CT = FT / 4;
    constexpr int GROUPS = 256 / CT;
    constexpr int NPB = GROUPS * NT;
    constexpr int NTILES = F / FT;
    const int t = blockIdx.x % NTILES;
    const int g = blockIdx.x / NTILES;
    const int ct = threadIdx.x % CT;
    const int gq = threadIdx.x / CT;

    for (int i = threadIdx.x; i < CIN * FT; i += 256) {
        const int k = i / FT, c = i % FT;
        wlds[i] = W[(size_t)k * F + t * FT + c];
    }
    __syncthreads();

    const int base = g * NPB + gq * NT;
    const float* xr[NT];
#pragma unroll
    for (int q = 0; q < NT; ++q) {
        const int node = base + q < n ? base + q : n - 1;
        xr[q] = X + (size_t)node * CIN;
    }
    float acc[NT][4];
#pragma unroll
    for (int q = 0; q < NT; ++q)
#pragma unroll
        for (int c = 0; c < 4; ++c) acc[q][c] = 0.f;

    for (int k = 0; k < CIN; k += 4) {
        const float* wr = wlds + k * FT + ct * 4;
        const float4 wa = *(const float4*)(wr);
        const float4 wb = *(const float4*)(wr + FT);
        const float4 wc = *(const float4*)(wr + 2 * FT);
        const float4 wd = *(const float4*)(wr + 3 * FT);
#pragma unroll
        for (int q = 0; q < NT; ++q) {
            const float4 x4 = *(const float4*)(xr[q] + k);
            acc[q][0] += x4.x * wa.x; acc[q][1] += x4.x * wa.y; acc[q][2] += x4.x * wa.z; acc[q][3] += x4.x * wa.w;
            acc[q][0] += x4.y * wb.x; acc[q][1] += x4.y * wb.y; acc[q][2] += x4.y * wb.z; acc[q][3] += x4.y * wb.w;
            acc[q][0] += x4.z * wc.x; acc[q][1] += x4.z * wc.y; acc[q][2] += x4.z * wc.z; acc[q][3] += x4.z * wc.w;
            acc[q][0] += x4.w * wd.x; acc[q][1] += x4.w * wd.y; acc[q][2] += x4.w * wd.z; acc[q][3] += x4.w * wd.w;
        }
    }
#pragma unroll
    for (int q = 0; q < NT; ++q) {
        if (base + q < n) {
            ushort4 r;
            r.x = f2b(acc[q][0]); r.y = f2b(acc[q][1]);
            r.z = f2b(acc[q][2]); r.w = f2b(acc[q][3]);
            *(ushort4*)(XL + (size_t)(base + q) * F + t * FT + ct * 4) = r;
        }
    }
}

// ---------- attention dots, wave per node (XL bf16) ----------
template<int F>
__global__ __launch_bounds__(256) void att_kernel(
    const unsigned short* __restrict__ XL,
    const float* __restrict__ att_s,
    const float* __restrict__ att_d,
    float* __restrict__ a_src, float* __restrict__ a_dst, int n)
{
    constexpr int CPL = F / 64;
    const int node = (blockIdx.x * 256 + threadIdx.x) >> 6;
    const int lane = threadIdx.x & 63;
    if (node >= n) return;
    const unsigned short* row = XL + (size_t)node * F + lane * CPL;
    float v[CPL];
    if constexpr (CPL == 2) {
        const unsigned int u = *(const unsigned int*)row;
        v[0] = b2f_bits(u & 0xffffu); v[1] = b2f_bits(u >> 16);
    } else {
        const uint2 u = *(const uint2*)row;
        v[0] = b2f_bits(u.x & 0xffffu); v[1] = b2f_bits(u.x >> 16);
        v[2] = b2f_bits(u.y & 0xffffu); v[3] = b2f_bits(u.y >> 16);
    }
    float s1 = 0.f, s2 = 0.f;
#pragma unroll
    for (int i = 0; i < CPL; ++i) {
        s1 += v[i] * att_s[lane * CPL + i];
        s2 += v[i] * att_d[lane * CPL + i];
    }
#pragma unroll
    for (int o = 1; o < 32; o <<= 1) {
        s1 += __shfl_xor(s1, o);
        s2 += __shfl_xor(s2, o);
    }
    if ((lane & 31) == 0) {
        const int head = lane >> 5;
        a_src[node * 2 + head] = s1;
        a_dst[node * 2 + head] = s2;
    }
}

// ---------- Pass A: radix-bucket edges by dst partition (both layers) ----------
// Each edge is read ONCE (coalesced) and appended as a packed 4B record
// (src | drel<<16, drel = d - part*PARTSZ, 13 bits) to one of 16 contiguous
// per-(layer,part) staging lists. Per-bucket positions via wave ballot +
// 4-wave LDS combine; ~8 global cursor atomics per block-iteration.
__global__ __launch_bounds__(256) void bucket_kernel(
    const int* __restrict__ e1, const int* __restrict__ e2, int ne,
    int* __restrict__ gcur, unsigned int* __restrict__ stage)
{
    const int layer = blockIdx.x & 1;
    const int* __restrict__ eix = layer ? e2 : e1;
    int* cur = gcur + layer * 8;
    unsigned int* __restrict__ stg = stage + (size_t)layer * 8 * SCAP;
    __shared__ int wcnt[4][8];
    __shared__ int gbase[8];
    const int wave = threadIdx.x >> 6;
    const int lane = threadIdx.x & 63;
    const unsigned long long lt = (1ull << lane) - 1ull;
    const int nbl = gridDim.x >> 1;
    const int bslot = blockIdx.x >> 1;

    for (int base = bslot * 512; base < ne; base += nbl * 512) {
        const int eA = base + threadIdx.x;
        const int eB = eA + 256;
        int pA = -1, pB = -1;
        unsigned int vA = 0, vB = 0;
        if (eA < ne) {
            const int s = eix[eA];
            const int d = eix[ne + eA];
            if ((unsigned)d < (unsigned)N_NODES) {
                pA = d / PARTSZ;
                vA = (unsigned)s | ((unsigned)(d - pA * PARTSZ) << 16);
            }
        }
        if (eB < ne) {
            const int s = eix[eB];
            const int d = eix[ne + eB];
            if ((unsigned)d < (unsigned)N_NODES) {
                pB = d / PARTSZ;
                vB = (unsigned)s | ((unsigned)(d - pB * PARTSZ) << 16);
            }
        }
        int posA = 0, posB = 0;
#pragma unroll
        for (int b = 0; b < 8; ++b) {
            const unsigned long long ma = __ballot(pA == b);
            const unsigned long long mb = __ballot(pB == b);
            if (pA == b) posA = __popcll(ma & lt);
            if (pB == b) posB = __popcll(ma) + __popcll(mb & lt);
            if (lane == b) wcnt[wave][b] = __popcll(ma) + __popcll(mb);
        }
        __syncthreads();
        if (threadIdx.x < 8) {
            const int b = threadIdx.x;
            const int c0 = wcnt[0][b], c1 = wcnt[1][b], c2 = wcnt[2][b], c3 = wcnt[3][b];
            const int tot = c0 + c1 + c2 + c3;
            gbase[b] = tot ? atomicAdd(&cur[b], tot) : 0;
            wcnt[0][b] = 0; wcnt[1][b] = c0; wcnt[2][b] = c0 + c1; wcnt[3][b] = c0 + c1 + c2;
        }
        __syncthreads();
        if (pA >= 0) {
            const int idx = gbase[pA] + wcnt[wave][pA] + posA;
            if (idx < SCAP) stg[(size_t)pA * SCAP + idx] = vA;
        }
        if (pB >= 0) {
            const int idx = gbase[pB] + wcnt[wave][pB] + posB;
            if (idx < SCAP) stg[(size_t)pB * SCAP + idx] = vB;
        }
        // no 3rd barrier needed: next-iter wcnt writes are own-wave; cross-wave
        // reads (tid<8) happen after the next __syncthreads.
    }
}

// ---------- Pass B: consume compacted per-partition lists, scatter into bins ----------
// blockIdx%8 == part keeps each partition's atomics+stores on one XCD
// (3.2MB footprint < 4MB L2 slice), same locality as before but with a
// coalesced 1x read of the list instead of an 8x scan of all edges.
__global__ __launch_bounds__(256) void scatter_kernel(
    const unsigned int* __restrict__ stage, const int* __restrict__ gcur,
    int* __restrict__ cnt1, int* __restrict__ cnt2,
    int* __restrict__ ss1, int* __restrict__ ss2)
{
    const int part  = blockIdx.x & 7;
    const int layer = (blockIdx.x >> 3) & 1;
    const int bslot = blockIdx.x >> 4;
    const int nbl   = gridDim.x >> 4;
    int m = gcur[layer * 8 + part];
    m = m < SCAP ? m : SCAP;
    const unsigned int* __restrict__ stg = stage + ((size_t)(layer * 8 + part)) * SCAP;
    int* __restrict__ cnt = layer ? cnt2 : cnt1;
    int* __restrict__ ss  = layer ? ss2 : ss1;
    const int dbase = part * PARTSZ;
    for (int i = bslot * 256 + threadIdx.x; i < m; i += nbl * 256) {
        const unsigned int v = stg[i];
        const int d = dbase + (int)(v >> 16);
        const int s = (int)(v & 0xffffu);
        const int slot = atomicAdd(&cnt[d], 1);
        if (slot < CAP) ss[(size_t)d * CAP + slot] = s;
    }
}

// ---------- fused softmax + aggregate (XL bf16, OUT f32), binned + self edge ----------
template<int F, int EPI>
__global__ __launch_bounds__(256) void aggregate_kernel(
    const unsigned short* __restrict__ XL,
    const float* __restrict__ a_src, const float* __restrict__ a_dst,
    const int* __restrict__ cnt, const int* __restrict__ src_bins,
    const float* __restrict__ bias,
    float* __restrict__ OUT, int n)
{
    constexpr int SUBW = 64 / EPI;
    static_assert(F / SUBW == 8, "8 cols per lane");
    constexpr int NB = 8 / EPI;

    const int node = (blockIdx.x * 256 + threadIdx.x) >> 6;
    const int lane = threadIdx.x & 63;
    if (node >= n) return;
    const int halfLane = lane & (SUBW - 1);
    const int sub = lane / SUBW;
    const int head = (halfLane >= SUBW / 2) ? 1 : 0;

    const int s = node * CAP;
    int deg = cnt[node];
    deg = deg < CAP ? deg : CAP;
    const int e = s + deg;
    const float2 ad2 = *(const float2*)(a_dst + node * 2);
    const float ahead = head ? ad2.y : ad2.x;

    float acc[8];
#pragma unroll
    for (int k = 0; k < 8; ++k) acc[k] = 0.f;
    float den = 0.f;

    int p = s;
    for (; p + 8 <= e; p += 8) {
        int j[NB];
#pragma unroll
        for (int g = 0; g < NB; ++g) j[g] = src_bins[p + g * EPI + sub];
        float A[NB];
#pragma unroll
        for (int g = 0; g < NB; ++g) A[g] = a_src[j[g] * 2 + head];
        uint4 u[NB];
#pragma unroll
        for (int g = 0; g < NB; ++g)
            u[g] = *(const uint4*)(XL + (size_t)j[g] * F + halfLane * 8);
#pragma unroll
        for (int g = 0; g < NB; ++g) {
            float l = A[g] + ahead;
            l = (l > 0.f) ? l : 0.2f * l;
            const float w = __expf(l);
            den += w;
            float f[8];
            unpack8(u[g], f);
#pragma unroll
            for (int k = 0; k < 8; ++k) acc[k] += w * f[k];
        }
    }
    for (; p < e; p += EPI) {
        const int pos = p + sub;
        const int pc = (pos < e) ? pos : (e - 1);
        const int j = src_bins[pc];
        const float A = a_src[j * 2 + head];
        const uint4 u = *(const uint4*)(XL + (size_t)j * F + halfLane * 8);
        float l = A + ahead;
        l = (l > 0.f) ? l : 0.2f * l;
        const float w = (pos < e) ? __expf(l) : 0.f;
        den += w;
        float f[8];
        unpack8(u, f);
#pragma unroll
        for (int k = 0; k < 8; ++k) acc[k] += w * f[k];
    }

    // implicit self-loop (j = node), added once by sub-wave 0
    if (sub == 0) {
        const float2 as2 = *(const float2*)(a_src + node * 2);
        float l = (head ? as2.y : as2.x) + ahead;
        l = (l > 0.f) ? l : 0.2f * l;
        const float w = __expf(l);
        den += w;
        const uint4 u = *(const uint4*)(XL + (size_t)node * F + halfLane * 8);
        float f[8];
        unpack8(u, f);
#pragma unroll
        for (int k = 0; k < 8; ++k) acc[k] += w * f[k];
    }

#pragma unroll
    for (int off = SUBW; off < 64; off <<= 1) {
        den += __shfl_xor(den, off);
#pragma unroll
        for (int k = 0; k < 8; ++k) acc[k] += __shfl_xor(acc[k], off);
    }

    if (sub == 0) {
        const float inv = 1.f / den;
        float* o = OUT + (size_t)node * F + halfLane * 8;
        const float* b = bias + halfLane * 8;
        float4 r0, r1;
        r0.x = acc[0] * inv + b[0]; r0.y = acc[1] * inv + b[1];
        r0.z = acc[2] * inv + b[2]; r0.w = acc[3] * inv + b[3];
        r1.x = acc[4] * inv + b[4]; r1.y = acc[5] * inv + b[5];
        r1.z = acc[6] * inv + b[6]; r1.w = acc[7] * inv + b[7];
        *(float4*)o = r0;
        *(float4*)(o + 4) = r1;
    }
}

// ---------- launch ----------
extern "C" void kernel_launch(void* const* d_in, const int* in_sizes, int n_in,
                              void* d_out, int out_size, void* d_ws, size_t ws_size,
                              hipStream_t stream)
{
    const int N = N_NODES, E = N_EDGES;

    const float* x   = (const float*)d_in[0];
    const int*   und = (const int*)d_in[1];
    const int*   dir = (const int*)d_in[2];
    const float* W1  = (const float*)d_in[3];
    const float* as1 = (const float*)d_in[4];
    const float* ad1 = (const float*)d_in[5];
    const float* b1  = (const float*)d_in[6];
    const float* W2  = (const float*)d_in[7];
    const float* as2 = (const float*)d_in[8];
    const float* ad2 = (const float*)d_in[9];
    const float* b2  = (const float*)d_in[10];

    char* p = (char*)d_ws;
    auto alloc = [&](size_t bytes) {
        char* r = p;
        p += (bytes + 255) & ~(size_t)255;
        return r;
    };
    unsigned short* xl1 = (unsigned short*)alloc((size_t)N * 128 * 2);  // bf16
    float*          h   = (float*)alloc((size_t)N * 128 * 4);           // f32
    unsigned short* xl2 = (unsigned short*)alloc((size_t)N * 256 * 2);  // bf16
    float* a_src   = (float*)alloc((size_t)N * 2 * 4);
    float* a_dst   = (float*)alloc((size_t)N * 2 * 4);
    int*   cnts    = (int*)alloc(((size_t)2 * N + 16) * 4);    // cnt1 | cnt2 | gcur
    int*   ss1     = (int*)alloc((size_t)N * CAP * 4);         // 12.8 MB bins
    int*   ss2     = (int*)alloc((size_t)N * CAP * 4);
    int* cnt1 = cnts, * cnt2 = cnts + N, * gcur = cnts + 2 * N;

    // staging for the radix pass aliases xl2 (16*SCAP*4 = 6.7MB < 25.6MB;
    // xl2 is only written later by gemm2, after scatter_kernel completed).
    unsigned int* stage = (unsigned int*)xl2;

    const int WB = (N * 64 + 255) / 256;     // wave-per-node blocks

    // ===== 2-pass XCD-partitioned edge binning for both layers =====
    hipMemsetAsync(cnts, 0, ((size_t)2 * N + 16) * 4, stream);
    bucket_kernel<<<1024, 256, 0, stream>>>(und, dir, E, gcur, stage);
    scatter_kernel<<<16 * 128, 256, 0, stream>>>(stage, gcur, cnt1, cnt2, ss1, ss2);

    // ===== Layer 1: Cin=64, F=128 (H=2, Fh=64), undirected edges =====
    gemm_kernel<64, 128, 128, 4><<<(N + 31) / 32, 256, 0, stream>>>(x, W1, xl1, N);
    att_kernel<128><<<WB, 256, 0, stream>>>(xl1, as1, ad1, a_src, a_dst, N);
    aggregate_kernel<128, 4><<<WB, 256, 0, stream>>>(xl1, a_src, a_dst, cnt1, ss1, b1, h, N);

    // ===== Layer 2: Cin=128, F=256 (H=2, Fh=128), directed edges =====
    gemm_kernel<128, 256, 64, 4><<<((N + 63) / 64) * 4, 256, 0, stream>>>(h, W2, xl2, N);
    att_kernel<256><<<WB, 256, 0, stream>>>(xl2, as2, ad2, a_src, a_dst, N);
    aggregate_kernel<256, 2><<<WB, 256, 0, stream>>>(xl2, a_src, a_dst, cnt2, ss2, b2,
                                                     (float*)d_out, N);
}

// Round 2
// 373.231 us; speedup vs baseline: 1.1186x; 1.1186x over previous
//
#include <hip/hip_runtime.h>
#include <stdint.h>

#define N_NODES 50000
#define N_EDGES 800000
#define CAP 64      // bin capacity for real (non-self) in-edges; Poisson(16) max over 50k ~44
#define NBUCK 400   // dst buckets per layer (125 dsts each)
#define BSZ 125     // dsts per bucket (NBUCK*BSZ == N_NODES)
#define BCAP 2816   // records per (layer,bucket); Poisson(2000) + ~18 sigma

// ---------- bf16 helpers ----------
__device__ __forceinline__ float b2f_bits(unsigned int lo16) {
    union { unsigned int i; float f; } v; v.i = lo16 << 16; return v.f;
}
__device__ __forceinline__ unsigned short f2b(float f) {
    union { float f; unsigned int i; } v; v.f = f;
    unsigned int x = v.i;
    return (unsigned short)((x + 0x7fffu + ((x >> 16) & 1u)) >> 16);
}
__device__ __forceinline__ void unpack8(const uint4 u, float* f) {
    f[0] = b2f_bits(u.x & 0xffffu); f[1] = b2f_bits(u.x >> 16);
    f[2] = b2f_bits(u.y & 0xffffu); f[3] = b2f_bits(u.y >> 16);
    f[4] = b2f_bits(u.z & 0xffffu); f[5] = b2f_bits(u.z >> 16);
    f[6] = b2f_bits(u.w & 0xffffu); f[7] = b2f_bits(u.w >> 16);
}

// ---------- GEMM: XL[n,F](bf16) = X[n,CIN](f32) @ W[CIN,F](f32) ----------
// tile-major mapping: all blocks of a pass share one F-tile; X re-reads hit L3.
template<int CIN, int F, int FT, int NT>
__global__ __launch_bounds__(256) void gemm_kernel(
    const float* __restrict__ X,
    const float* __restrict__ W,
    unsigned short* __restrict__ XL, int n)
{
    __shared__ float wlds[CIN * FT];
    constexpr int CT = FT / 4;
    constexpr int GROUPS = 256 / CT;
    constexpr int NPB = GROUPS * NT;
    constexpr int NTILES = F / FT;
    const int ngb = gridDim.x / NTILES;
    const int t = blockIdx.x / ngb;          // F-tile index (slow)
    const int g = blockIdx.x % ngb;          // node-group index (fast)
    const int ct = threadIdx.x % CT;
    const int gq = threadIdx.x / CT;

    for (int i = threadIdx.x; i < CIN * FT; i += 256) {
        const int k = i / FT, c = i % FT;
        wlds[i] = W[(size_t)k * F + t * FT + c];
    }
    __syncthreads();

    const int base = g * NPB + gq * NT;
    const float* xr[NT];
#pragma unroll
    for (int q = 0; q < NT; ++q) {
        const int node = base + q < n ? base + q : n - 1;
        xr[q] = X + (size_t)node * CIN;
    }
    float acc[NT][4];
#pragma unroll
    for (int q = 0; q < NT; ++q)
#pragma unroll
        for (int c = 0; c < 4; ++c) acc[q][c] = 0.f;

    for (int k = 0; k < CIN; k += 4) {
        const float* wr = wlds + k * FT + ct * 4;
        const float4 wa = *(const float4*)(wr);
        const float4 wb = *(const float4*)(wr + FT);
        const float4 wc = *(const float4*)(wr + 2 * FT);
        const float4 wd = *(const float4*)(wr + 3 * FT);
#pragma unroll
        for (int q = 0; q < NT; ++q) {
            const float4 x4 = *(const float4*)(xr[q] + k);
            acc[q][0] += x4.x * wa.x; acc[q][1] += x4.x * wa.y; acc[q][2] += x4.x * wa.z; acc[q][3] += x4.x * wa.w;
            acc[q][0] += x4.y * wb.x; acc[q][1] += x4.y * wb.y; acc[q][2] += x4.y * wb.z; acc[q][3] += x4.y * wb.w;
            acc[q][0] += x4.z * wc.x; acc[q][1] += x4.z * wc.y; acc[q][2] += x4.z * wc.z; acc[q][3] += x4.z * wc.w;
            acc[q][0] += x4.w * wd.x; acc[q][1] += x4.w * wd.y; acc[q][2] += x4.w * wd.z; acc[q][3] += x4.w * wd.w;
        }
    }
#pragma unroll
    for (int q = 0; q < NT; ++q) {
        if (base + q < n) {
            ushort4 r;
            r.x = f2b(acc[q][0]); r.y = f2b(acc[q][1]);
            r.z = f2b(acc[q][2]); r.w = f2b(acc[q][3]);
            *(ushort4*)(XL + (size_t)(base + q) * F + t * FT + ct * 4) = r;
        }
    }
}

// ---------- attention dots, wave per node (XL bf16) ----------
template<int F>
__global__ __launch_bounds__(256) void att_kernel(
    const unsigned short* __restrict__ XL,
    const float* __restrict__ att_s,
    const float* __restrict__ att_d,
    float* __restrict__ a_src, float* __restrict__ a_dst, int n)
{
    constexpr int CPL = F / 64;
    const int node = (blockIdx.x * 256 + threadIdx.x) >> 6;
    const int lane = threadIdx.x & 63;
    if (node >= n) return;
    const unsigned short* row = XL + (size_t)node * F + lane * CPL;
    float v[CPL];
    if constexpr (CPL == 2) {
        const unsigned int u = *(const unsigned int*)row;
        v[0] = b2f_bits(u & 0xffffu); v[1] = b2f_bits(u >> 16);
    } else {
        const uint2 u = *(const uint2*)row;
        v[0] = b2f_bits(u.x & 0xffffu); v[1] = b2f_bits(u.x >> 16);
        v[2] = b2f_bits(u.y & 0xffffu); v[3] = b2f_bits(u.y >> 16);
    }
    float s1 = 0.f, s2 = 0.f;
#pragma unroll
    for (int i = 0; i < CPL; ++i) {
        s1 += v[i] * att_s[lane * CPL + i];
        s2 += v[i] * att_d[lane * CPL + i];
    }
#pragma unroll
    for (int o = 1; o < 32; o <<= 1) {
        s1 += __shfl_xor(s1, o);
        s2 += __shfl_xor(s2, o);
    }
    if ((lane & 31) == 0) {
        const int head = lane >> 5;
        a_src[node * 2 + head] = s1;
        a_dst[node * 2 + head] = s2;
    }
}

// ---------- Pass A: radix-bucket edges into 400 dst-buckets per layer ----------
// Edges read once, coalesced. Per-block LDS histogram -> ONE global cursor
// atomic per (bucket,block); records placed via LDS atomics. No per-edge
// global atomics. Record: src | drel<<16 (drel < 125).
__global__ __launch_bounds__(256) void bucket_kernel(
    const int* __restrict__ e1, const int* __restrict__ e2, int ne,
    int* __restrict__ gcur, unsigned int* __restrict__ stage)
{
    const int layer = blockIdx.x & 1;
    const int bslot = blockIdx.x >> 1;
    const int nbl = gridDim.x >> 1;
    const int* __restrict__ eix = layer ? e2 : e1;
    int* cur = gcur + layer * NBUCK;
    unsigned int* __restrict__ stg = stage + (size_t)layer * NBUCK * BCAP;

    __shared__ int cnt_lds[NBUCK];
    __shared__ int base_lds[NBUCK];
    constexpr int EPT = 16;
    constexpr int CHUNK = 256 * EPT;   // 4096 edges per block-chunk

    for (int base = bslot * CHUNK; base < ne; base += nbl * CHUNK) {
        for (int i = threadIdx.x; i < NBUCK; i += 256) cnt_lds[i] = 0;
        __syncthreads();

        unsigned int rec[EPT];
        int bk[EPT];
#pragma unroll
        for (int i = 0; i < EPT; ++i) {
            const int e = base + i * 256 + threadIdx.x;
            bk[i] = -1;
            if (e < ne) {
                const int s = eix[e];
                const int d = eix[ne + e];
                if ((unsigned)d < (unsigned)N_NODES) {
                    const int b = d / BSZ;
                    bk[i] = b;
                    rec[i] = (unsigned)s | ((unsigned)(d - b * BSZ) << 16);
                    atomicAdd(&cnt_lds[b], 1);
                }
            }
        }
        __syncthreads();
        for (int i = threadIdx.x; i < NBUCK; i += 256) {
            const int c = cnt_lds[i];
            base_lds[i] = c ? atomicAdd(&cur[i], c) : 0;
            cnt_lds[i] = 0;
        }
        __syncthreads();
#pragma unroll
        for (int i = 0; i < EPT; ++i) {
            if (bk[i] >= 0) {
                const int idx = base_lds[bk[i]] + atomicAdd(&cnt_lds[bk[i]], 1);
                if (idx < BCAP) stg[(size_t)bk[i] * BCAP + idx] = rec[i];
            }
        }
        __syncthreads();   // protect cnt_lds before next chunk's zeroing
    }
}

// ---------- Pass B: one block per (layer,bucket); LDS counting-sort ----------
// Slots assigned by LDS atomics into a 125x64 in-LDS bin image, then the
// whole image is dumped coalesced (uint4) into the global ss layout.
// Writes cnt[] for every dst (no memset needed; garbage slots never read).
__global__ __launch_bounds__(256) void place_kernel(
    const unsigned int* __restrict__ stage, const int* __restrict__ gcur,
    int* __restrict__ cnt1, int* __restrict__ cnt2,
    int* __restrict__ ss1, int* __restrict__ ss2)
{
    const int layer = blockIdx.x & 1;
    const int bucket = blockIdx.x >> 1;
    int m = gcur[layer * NBUCK + bucket];
    m = m < BCAP ? m : BCAP;
    const unsigned int* __restrict__ stg =
        stage + ((size_t)(layer * NBUCK + bucket)) * BCAP;
    int* __restrict__ cnt = layer ? cnt2 : cnt1;
    int* __restrict__ ss  = layer ? ss2 : ss1;
    const int d0 = bucket * BSZ;

    __shared__ int c_lds[BSZ];
    __shared__ __align__(16) unsigned int img[BSZ * CAP];   // 32000 B

    for (int i = threadIdx.x; i < BSZ; i += 256) c_lds[i] = 0;
    __syncthreads();

    for (int i = threadIdx.x; i < m; i += 256) {
        const unsigned int v = stg[i];
        const int dr = (int)(v >> 16);
        const int slot = atomicAdd(&c_lds[dr], 1);
        if (slot < CAP) img[dr * CAP + slot] = v & 0xffffu;
    }
    __syncthreads();

    // coalesced dump of the full image (garbage slots beyond cnt unread)
    uint4* dst4 = (uint4*)(ss + (size_t)d0 * CAP);
    const uint4* src4 = (const uint4*)img;
    constexpr int NV4 = BSZ * CAP / 4;   // 2000
    for (int i = threadIdx.x; i < NV4; i += 256) dst4[i] = src4[i];
    for (int i = threadIdx.x; i < BSZ; i += 256) {
        const int c = c_lds[i];
        cnt[d0 + i] = c < CAP ? c : CAP;
    }
}

// ---------- fused softmax + aggregate (XL bf16, OUT f32), binned + self edge ----------
template<int F, int EPI>
__global__ __launch_bounds__(256) void aggregate_kernel(
    const unsigned short* __restrict__ XL,
    const float* __restrict__ a_src, const float* __restrict__ a_dst,
    const int* __restrict__ cnt, const int* __restrict__ src_bins,
    const float* __restrict__ bias,
    float* __restrict__ OUT, int n)
{
    constexpr int SUBW = 64 / EPI;
    static_assert(F / SUBW == 8, "8 cols per lane");
    constexpr int NB = 8 / EPI;

    const int node = (blockIdx.x * 256 + threadIdx.x) >> 6;
    const int lane = threadIdx.x & 63;
    if (node >= n) return;
    const int halfLane = lane & (SUBW - 1);
    const int sub = lane / SUBW;
    const int head = (halfLane >= SUBW / 2) ? 1 : 0;

    const int s = node * CAP;
    int deg = cnt[node];
    deg = deg < CAP ? deg : CAP;
    const int e = s + deg;
    const float2 ad2 = *(const float2*)(a_dst + node * 2);
    const float ahead = head ? ad2.y : ad2.x;

    float acc[8];
#pragma unroll
    for (int k = 0; k < 8; ++k) acc[k] = 0.f;
    float den = 0.f;

    int p = s;
    for (; p + 8 <= e; p += 8) {
        int j[NB];
#pragma unroll
        for (int g = 0; g < NB; ++g) j[g] = src_bins[p + g * EPI + sub];
        float A[NB];
#pragma unroll
        for (int g = 0; g < NB; ++g) A[g] = a_src[j[g] * 2 + head];
        uint4 u[NB];
#pragma unroll
        for (int g = 0; g < NB; ++g)
            u[g] = *(const uint4*)(XL + (size_t)j[g] * F + halfLane * 8);
#pragma unroll
        for (int g = 0; g < NB; ++g) {
            float l = A[g] + ahead;
            l = (l > 0.f) ? l : 0.2f * l;
            const float w = __expf(l);
            den += w;
            float f[8];
            unpack8(u[g], f);
#pragma unroll
            for (int k = 0; k < 8; ++k) acc[k] += w * f[k];
        }
    }
    for (; p < e; p += EPI) {
        const int pos = p + sub;
        const int pc = (pos < e) ? pos : (e - 1);
        const int j = src_bins[pc];
        const float A = a_src[j * 2 + head];
        const uint4 u = *(const uint4*)(XL + (size_t)j * F + halfLane * 8);
        float l = A + ahead;
        l = (l > 0.f) ? l : 0.2f * l;
        const float w = (pos < e) ? __expf(l) : 0.f;
        den += w;
        float f[8];
        unpack8(u, f);
#pragma unroll
        for (int k = 0; k < 8; ++k) acc[k] += w * f[k];
    }

    // implicit self-loop (j = node), added once by sub-wave 0
    if (sub == 0) {
        const float2 as2 = *(const float2*)(a_src + node * 2);
        float l = (head ? as2.y : as2.x) + ahead;
        l = (l > 0.f) ? l : 0.2f * l;
        const float w = __expf(l);
        den += w;
        const uint4 u = *(const uint4*)(XL + (size_t)node * F + halfLane * 8);
        float f[8];
        unpack8(u, f);
#pragma unroll
        for (int k = 0; k < 8; ++k) acc[k] += w * f[k];
    }

#pragma unroll
    for (int off = SUBW; off < 64; off <<= 1) {
        den += __shfl_xor(den, off);
#pragma unroll
        for (int k = 0; k < 8; ++k) acc[k] += __shfl_xor(acc[k], off);
    }

    if (sub == 0) {
        const float inv = 1.f / den;
        float* o = OUT + (size_t)node * F + halfLane * 8;
        const float* b = bias + halfLane * 8;
        float4 r0, r1;
        r0.x = acc[0] * inv + b[0]; r0.y = acc[1] * inv + b[1];
        r0.z = acc[2] * inv + b[2]; r0.w = acc[3] * inv + b[3];
        r1.x = acc[4] * inv + b[4]; r1.y = acc[5] * inv + b[5];
        r1.z = acc[6] * inv + b[6]; r1.w = acc[7] * inv + b[7];
        *(float4*)o = r0;
        *(float4*)(o + 4) = r1;
    }
}

// ---------- launch ----------
extern "C" void kernel_launch(void* const* d_in, const int* in_sizes, int n_in,
                              void* d_out, int out_size, void* d_ws, size_t ws_size,
                              hipStream_t stream)
{
    const int N = N_NODES, E = N_EDGES;

    const float* x   = (const float*)d_in[0];
    const int*   und = (const int*)d_in[1];
    const int*   dir = (const int*)d_in[2];
    const float* W1  = (const float*)d_in[3];
    const float* as1 = (const float*)d_in[4];
    const float* ad1 = (const float*)d_in[5];
    const float* b1  = (const float*)d_in[6];
    const float* W2  = (const float*)d_in[7];
    const float* as2 = (const float*)d_in[8];
    const float* ad2 = (const float*)d_in[9];
    const float* b2  = (const float*)d_in[10];

    char* p = (char*)d_ws;
    auto alloc = [&](size_t bytes) {
        char* r = p;
        p += (bytes + 255) & ~(size_t)255;
        return r;
    };
    unsigned short* xl1 = (unsigned short*)alloc((size_t)N * 128 * 2);  // bf16
    float*          h   = (float*)alloc((size_t)N * 128 * 4);           // f32
    unsigned short* xl2 = (unsigned short*)alloc((size_t)N * 256 * 2);  // bf16
    float* a_src   = (float*)alloc((size_t)N * 2 * 4);
    float* a_dst   = (float*)alloc((size_t)N * 2 * 4);
    int*   cnts    = (int*)alloc(((size_t)2 * N + 2 * NBUCK) * 4);
    int*   ss1     = (int*)alloc((size_t)N * CAP * 4);         // 12.8 MB bins
    int*   ss2     = (int*)alloc((size_t)N * CAP * 4);
    int* cnt1 = cnts, * cnt2 = cnts + N, * gcur = cnts + 2 * N;

    // staging for the radix pass aliases xl2 (2*400*2816*4 = 9.0MB < 25.6MB;
    // xl2 is only written later by gemm2, after place_kernel completed).
    unsigned int* stage = (unsigned int*)xl2;

    const int WB = (N * 64 + 255) / 256;     // wave-per-node blocks

    // ===== 2-level LDS counting-sort edge binning, both layers =====
    hipMemsetAsync(gcur, 0, (size_t)2 * NBUCK * 4, stream);
    bucket_kernel<<<2 * 196, 256, 0, stream>>>(und, dir, E, gcur, stage);
    place_kernel<<<2 * NBUCK, 256, 0, stream>>>(stage, gcur, cnt1, cnt2, ss1, ss2);

    // ===== Layer 1: Cin=64, F=128 (H=2, Fh=64), undirected edges =====
    gemm_kernel<64, 128, 64, 4><<<((N + 63) / 64) * 2, 256, 0, stream>>>(x, W1, xl1, N);
    att_kernel<128><<<WB, 256, 0, stream>>>(xl1, as1, ad1, a_src, a_dst, N);
    aggregate_kernel<128, 4><<<WB, 256, 0, stream>>>(xl1, a_src, a_dst, cnt1, ss1, b1, h, N);

    // ===== Layer 2: Cin=128, F=256 (H=2, Fh=128), directed edges =====
    gemm_kernel<128, 256, 32, 4><<<((N + 127) / 128) * 8, 256, 0, stream>>>(h, W2, xl2, N);
    att_kernel<256><<<WB, 256, 0, stream>>>(xl2, as2, ad2, a_src, a_dst, N);
    aggregate_kernel<256, 2><<<WB, 256, 0, stream>>>(xl2, a_src, a_dst, cnt2, ss2, b2,
                                                     (float*)d_out, N);
}

// Round 3
// 308.323 us; speedup vs baseline: 1.3540x; 1.2105x over previous
//
#include <hip/hip_runtime.h>
#include <stdint.h>

#define N_NODES 50000
#define N_EDGES 800000
#define CAP 64      // bin capacity for real (non-self) in-edges; Poisson(16) max over 50k ~44
#define NBUCK 400   // dst buckets per layer (125 dsts each)
#define BSZ 125     // dsts per bucket (NBUCK*BSZ == N_NODES)
#define BCAP 2816   // records per (layer,bucket); Poisson(2000) + ~18 sigma

typedef __attribute__((ext_vector_type(8))) short bf16x8;  // 8 bf16 = 4 VGPR
typedef __attribute__((ext_vector_type(4))) float f32x4;   // MFMA acc

// ---------- bf16 helpers ----------
__device__ __forceinline__ float b2f_bits(unsigned int lo16) {
    union { unsigned int i; float f; } v; v.i = lo16 << 16; return v.f;
}
__device__ __forceinline__ unsigned short f2b(float f) {
    union { float f; unsigned int i; } v; v.f = f;
    unsigned int x = v.i;
    return (unsigned short)((x + 0x7fffu + ((x >> 16) & 1u)) >> 16);
}
__device__ __forceinline__ void split2(float v, unsigned short& h, unsigned short& l) {
    h = f2b(v);
    l = f2b(v - b2f_bits(h));
}
__device__ __forceinline__ void unpack8(const uint4 u, float* f) {
    f[0] = b2f_bits(u.x & 0xffffu); f[1] = b2f_bits(u.x >> 16);
    f[2] = b2f_bits(u.y & 0xffffu); f[3] = b2f_bits(u.y >> 16);
    f[4] = b2f_bits(u.z & 0xffffu); f[5] = b2f_bits(u.z >> 16);
    f[6] = b2f_bits(u.w & 0xffffu); f[7] = b2f_bits(u.w >> 16);
}

// ---------- prep: split f32 -> (hi,lo) bf16, elementwise (vectorized) ----------
__global__ __launch_bounds__(256) void splitX_kernel(
    const float* __restrict__ X,
    unsigned short* __restrict__ Xh, unsigned short* __restrict__ Xl, int total4)
{
    const int i = blockIdx.x * 256 + threadIdx.x;
    if (i >= total4) return;
    const float4 v = ((const float4*)X)[i];
    ushort4 h, l;
    split2(v.x, h.x, l.x); split2(v.y, h.y, l.y);
    split2(v.z, h.z, l.z); split2(v.w, h.w, l.w);
    ((ushort4*)Xh)[i] = h;
    ((ushort4*)Xl)[i] = l;
}

// ---------- prep: W[K,N] f32 -> WhT,WlT [N,K] bf16 (transposed + split) ----------
__global__ __launch_bounds__(256) void splitWT_kernel(
    const float* __restrict__ W,
    unsigned short* __restrict__ WhT, unsigned short* __restrict__ WlT, int K, int N)
{
    const int i = blockIdx.x * 256 + threadIdx.x;
    if (i >= N * K) return;
    const int n = i / K, k = i % K;
    const float v = W[(size_t)k * N + n];
    unsigned short h, l;
    split2(v, h, l);
    WhT[i] = h; WlT[i] = l;
}

// ---------- split-bf16 MFMA GEMM: XL[M,N](bf16) = X[M,K](hi+lo) @ W[K,N](hi+lo)
// Exact-to-~2^-17: Xh@Wh + Xl@Wh + Xh@Wl. Operands swapped (A=W^T tile,
// B=X tile) so each lane's 4 acc regs are 4 CONSECUTIVE output columns ->
// contiguous ushort4 stores. W frags persist in registers for the whole
// kernel; X frags are register-double-buffered across 16-row strips.
// 8 waves/block, wave w owns cols [w*CT*16, (w+1)*CT*16).
template<int K, int N, int CT>
__global__ __launch_bounds__(512) void mfma_gemm_kernel(
    const unsigned short* __restrict__ Xh,   // [M,K] bf16 hi
    const unsigned short* __restrict__ Xl,   // [M,K] bf16 lo
    const unsigned short* __restrict__ WhT,  // [N,K] bf16 hi
    const unsigned short* __restrict__ WlT,  // [N,K] bf16 lo
    unsigned short* __restrict__ XL, int M)
{
    constexpr int KC = K / 32;               // k-chunks of 32
    const int wave = threadIdx.x >> 6;
    const int lane = threadIdx.x & 63;
    const int lr = lane & 15;                // row selector within 16-tile
    const int lk = (lane >> 4) * 8;          // k offset (elements)
    const int c0 = wave * CT * 16;           // this wave's first output col

    // persistent W fragments (A-operand): aw[tile][chunk]
    bf16x8 aw_h[CT][KC], aw_l[CT][KC];
#pragma unroll
    for (int t = 0; t < CT; ++t) {
        const unsigned short* wr  = WhT + (size_t)(c0 + t * 16 + lr) * K + lk;
        const unsigned short* wr2 = WlT + (size_t)(c0 + t * 16 + lr) * K + lk;
#pragma unroll
        for (int c = 0; c < KC; ++c) {
            aw_h[t][c] = *(const bf16x8*)(wr + c * 32);
            aw_l[t][c] = *(const bf16x8*)(wr2 + c * 32);
        }
    }

    auto loadB = [&](bf16x8 (&bh)[KC], bf16x8 (&bl)[KC], int sidx) {
        const unsigned short* xr  = Xh + (size_t)(sidx * 16 + lr) * K + lk;
        const unsigned short* xr2 = Xl + (size_t)(sidx * 16 + lr) * K + lk;
#pragma unroll
        for (int c = 0; c < KC; ++c) {
            bh[c] = *(const bf16x8*)(xr + c * 32);
            bl[c] = *(const bf16x8*)(xr2 + c * 32);
        }
    };
    auto compute = [&](bf16x8 (&bh)[KC], bf16x8 (&bl)[KC], int sidx) {
#pragma unroll
        for (int t = 0; t < CT; ++t) {
            f32x4 acc = {0.f, 0.f, 0.f, 0.f};
#pragma unroll
            for (int c = 0; c < KC; ++c)
                acc = __builtin_amdgcn_mfma_f32_16x16x32_bf16(aw_h[t][c], bh[c], acc, 0, 0, 0);
#pragma unroll
            for (int c = 0; c < KC; ++c)
                acc = __builtin_amdgcn_mfma_f32_16x16x32_bf16(aw_h[t][c], bl[c], acc, 0, 0, 0);
#pragma unroll
            for (int c = 0; c < KC; ++c)
                acc = __builtin_amdgcn_mfma_f32_16x16x32_bf16(aw_l[t][c], bh[c], acc, 0, 0, 0);
            // D: col(of D)=lane&15 -> node row; row(of D)=(lane>>4)*4+reg -> out col
            ushort4 r;
            r.x = f2b(acc[0]); r.y = f2b(acc[1]); r.z = f2b(acc[2]); r.w = f2b(acc[3]);
            *(ushort4*)(XL + (size_t)(sidx * 16 + lr) * N + c0 + t * 16 + ((lane >> 4) << 2)) = r;
        }
    };

    const int NSTRIP = M / 16;   // 3125, exact
    const int nb = gridDim.x;
    int s = blockIdx.x;
    bf16x8 b0h[KC], b0l[KC], b1h[KC], b1l[KC];
    if (s < NSTRIP) loadB(b0h, b0l, s);
    while (s < NSTRIP) {
        const int sn = s + nb;
        if (sn < NSTRIP) loadB(b1h, b1l, sn);
        compute(b0h, b0l, s);
        if (sn >= NSTRIP) break;
        const int sn2 = sn + nb;
        if (sn2 < NSTRIP) loadB(b0h, b0l, sn2);
        compute(b1h, b1l, sn);
        s = sn2;
    }
}

// ---------- attention dots, wave per node (XL bf16) ----------
template<int F>
__global__ __launch_bounds__(256) void att_kernel(
    const unsigned short* __restrict__ XL,
    const float* __restrict__ att_s,
    const float* __restrict__ att_d,
    float* __restrict__ a_src, float* __restrict__ a_dst, int n)
{
    constexpr int CPL = F / 64;
    const int node = (blockIdx.x * 256 + threadIdx.x) >> 6;
    const int lane = threadIdx.x & 63;
    if (node >= n) return;
    const unsigned short* row = XL + (size_t)node * F + lane * CPL;
    float v[CPL];
    if constexpr (CPL == 2) {
        const unsigned int u = *(const unsigned int*)row;
        v[0] = b2f_bits(u & 0xffffu); v[1] = b2f_bits(u >> 16);
    } else {
        const uint2 u = *(const uint2*)row;
        v[0] = b2f_bits(u.x & 0xffffu); v[1] = b2f_bits(u.x >> 16);
        v[2] = b2f_bits(u.y & 0xffffu); v[3] = b2f_bits(u.y >> 16);
    }
    float s1 = 0.f, s2 = 0.f;
#pragma unroll
    for (int i = 0; i < CPL; ++i) {
        s1 += v[i] * att_s[lane * CPL + i];
        s2 += v[i] * att_d[lane * CPL + i];
    }
#pragma unroll
    for (int o = 1; o < 32; o <<= 1) {
        s1 += __shfl_xor(s1, o);
        s2 += __shfl_xor(s2, o);
    }
    if ((lane & 31) == 0) {
        const int head = lane >> 5;
        a_src[node * 2 + head] = s1;
        a_dst[node * 2 + head] = s2;
    }
}

// ---------- Pass A: radix-bucket edges into 400 dst-buckets per layer ----------
__global__ __launch_bounds__(256) void bucket_kernel(
    const int* __restrict__ e1, const int* __restrict__ e2, int ne,
    int* __restrict__ gcur, unsigned int* __restrict__ stage)
{
    const int layer = blockIdx.x & 1;
    const int bslot = blockIdx.x >> 1;
    const int nbl = gridDim.x >> 1;
    const int* __restrict__ eix = layer ? e2 : e1;
    int* cur = gcur + layer * NBUCK;
    unsigned int* __restrict__ stg = stage + (size_t)layer * NBUCK * BCAP;

    __shared__ int cnt_lds[NBUCK];
    __shared__ int base_lds[NBUCK];
    constexpr int EPT = 16;
    constexpr int CHUNK = 256 * EPT;

    for (int base = bslot * CHUNK; base < ne; base += nbl * CHUNK) {
        for (int i = threadIdx.x; i < NBUCK; i += 256) cnt_lds[i] = 0;
        __syncthreads();

        unsigned int rec[EPT];
        int bk[EPT];
#pragma unroll
        for (int i = 0; i < EPT; ++i) {
            const int e = base + i * 256 + threadIdx.x;
            bk[i] = -1;
            if (e < ne) {
                const int s = eix[e];
                const int d = eix[ne + e];
                if ((unsigned)d < (unsigned)N_NODES) {
                    const int b = d / BSZ;
                    bk[i] = b;
                    rec[i] = (unsigned)s | ((unsigned)(d - b * BSZ) << 16);
                    atomicAdd(&cnt_lds[b], 1);
                }
            }
        }
        __syncthreads();
        for (int i = threadIdx.x; i < NBUCK; i += 256) {
            const int c = cnt_lds[i];
            base_lds[i] = c ? atomicAdd(&cur[i], c) : 0;
            cnt_lds[i] = 0;
        }
        __syncthreads();
#pragma unroll
        for (int i = 0; i < EPT; ++i) {
            if (bk[i] >= 0) {
                const int idx = base_lds[bk[i]] + atomicAdd(&cnt_lds[bk[i]], 1);
                if (idx < BCAP) stg[(size_t)bk[i] * BCAP + idx] = rec[i];
            }
        }
        __syncthreads();
    }
}

// ---------- Pass B: one block per (layer,bucket); LDS counting-sort ----------
__global__ __launch_bounds__(256) void place_kernel(
    const unsigned int* __restrict__ stage, const int* __restrict__ gcur,
    int* __restrict__ cnt1, int* __restrict__ cnt2,
    int* __restrict__ ss1, int* __restrict__ ss2)
{
    const int layer = blockIdx.x & 1;
    const int bucket = blockIdx.x >> 1;
    int m = gcur[layer * NBUCK + bucket];
    m = m < BCAP ? m : BCAP;
    const unsigned int* __restrict__ stg =
        stage + ((size_t)(layer * NBUCK + bucket)) * BCAP;
    int* __restrict__ cnt = layer ? cnt2 : cnt1;
    int* __restrict__ ss  = layer ? ss2 : ss1;
    const int d0 = bucket * BSZ;

    __shared__ int c_lds[BSZ];
    __shared__ __align__(16) unsigned int img[BSZ * CAP];

    for (int i = threadIdx.x; i < BSZ; i += 256) c_lds[i] = 0;
    __syncthreads();

    for (int i = threadIdx.x; i < m; i += 256) {
        const unsigned int v = stg[i];
        const int dr = (int)(v >> 16);
        const int slot = atomicAdd(&c_lds[dr], 1);
        if (slot < CAP) img[dr * CAP + slot] = v & 0xffffu;
    }
    __syncthreads();

    uint4* dst4 = (uint4*)(ss + (size_t)d0 * CAP);
    const uint4* src4 = (const uint4*)img;
    constexpr int NV4 = BSZ * CAP / 4;
    for (int i = threadIdx.x; i < NV4; i += 256) dst4[i] = src4[i];
    for (int i = threadIdx.x; i < BSZ; i += 256) {
        const int c = c_lds[i];
        cnt[d0 + i] = c < CAP ? c : CAP;
    }
}

// ---------- fused softmax + aggregate (XL bf16), binned + self edge ----------
// SPLIT=true: emit hi/lo bf16 (for next layer's MFMA GEMM) instead of f32.
template<int F, int EPI, bool SPLIT>
__global__ __launch_bounds__(256) void aggregate_kernel(
    const unsigned short* __restrict__ XL,
    const float* __restrict__ a_src, const float* __restrict__ a_dst,
    const int* __restrict__ cnt, const int* __restrict__ src_bins,
    const float* __restrict__ bias,
    float* __restrict__ OUT,
    unsigned short* __restrict__ OH, unsigned short* __restrict__ OL, int n)
{
    constexpr int SUBW = 64 / EPI;
    static_assert(F / SUBW == 8, "8 cols per lane");
    constexpr int NB = 8 / EPI;

    const int node = (blockIdx.x * 256 + threadIdx.x) >> 6;
    const int lane = threadIdx.x & 63;
    if (node >= n) return;
    const int halfLane = lane & (SUBW - 1);
    const int sub = lane / SUBW;
    const int head = (halfLane >= SUBW / 2) ? 1 : 0;

    const int s = node * CAP;
    int deg = cnt[node];
    deg = deg < CAP ? deg : CAP;
    const int e = s + deg;
    const float2 ad2 = *(const float2*)(a_dst + node * 2);
    const float ahead = head ? ad2.y : ad2.x;

    float acc[8];
#pragma unroll
    for (int k = 0; k < 8; ++k) acc[k] = 0.f;
    float den = 0.f;

    int p = s;
    for (; p + 8 <= e; p += 8) {
        int j[NB];
#pragma unroll
        for (int g = 0; g < NB; ++g) j[g] = src_bins[p + g * EPI + sub];
        float A[NB];
#pragma unroll
        for (int g = 0; g < NB; ++g) A[g] = a_src[j[g] * 2 + head];
        uint4 u[NB];
#pragma unroll
        for (int g = 0; g < NB; ++g)
            u[g] = *(const uint4*)(XL + (size_t)j[g] * F + halfLane * 8);
#pragma unroll
        for (int g = 0; g < NB; ++g) {
            float l = A[g] + ahead;
            l = (l > 0.f) ? l : 0.2f * l;
            const float w = __expf(l);
            den += w;
            float f[8];
            unpack8(u[g], f);
#pragma unroll
            for (int k = 0; k < 8; ++k) acc[k] += w * f[k];
        }
    }
    for (; p < e; p += EPI) {
        const int pos = p + sub;
        const int pc = (pos < e) ? pos : (e - 1);
        const int j = src_bins[pc];
        const float A = a_src[j * 2 + head];
        const uint4 u = *(const uint4*)(XL + (size_t)j * F + halfLane * 8);
        float l = A + ahead;
        l = (l > 0.f) ? l : 0.2f * l;
        const float w = (pos < e) ? __expf(l) : 0.f;
        den += w;
        float f[8];
        unpack8(u, f);
#pragma unroll
        for (int k = 0; k < 8; ++k) acc[k] += w * f[k];
    }

    // implicit self-loop (j = node), added once by sub-wave 0
    if (sub == 0) {
        const float2 as2 = *(const float2*)(a_src + node * 2);
        float l = (head ? as2.y : as2.x) + ahead;
        l = (l > 0.f) ? l : 0.2f * l;
        const float w = __expf(l);
        den += w;
        const uint4 u = *(const uint4*)(XL + (size_t)node * F + halfLane * 8);
        float f[8];
        unpack8(u, f);
#pragma unroll
        for (int k = 0; k < 8; ++k) acc[k] += w * f[k];
    }

#pragma unroll
    for (int off = SUBW; off < 64; off <<= 1) {
        den += __shfl_xor(den, off);
#pragma unroll
        for (int k = 0; k < 8; ++k) acc[k] += __shfl_xor(acc[k], off);
    }

    if (sub == 0) {
        const float inv = 1.f / den;
        const float* b = bias + halfLane * 8;
        float vals[8];
#pragma unroll
        for (int k = 0; k < 8; ++k) vals[k] = acc[k] * inv + b[k];
        if constexpr (SPLIT) {
            ushort4 h0, h1, l0, l1;
            split2(vals[0], h0.x, l0.x); split2(vals[1], h0.y, l0.y);
            split2(vals[2], h0.z, l0.z); split2(vals[3], h0.w, l0.w);
            split2(vals[4], h1.x, l1.x); split2(vals[5], h1.y, l1.y);
            split2(vals[6], h1.z, l1.z); split2(vals[7], h1.w, l1.w);
            unsigned short* oh = OH + (size_t)node * F + halfLane * 8;
            unsigned short* ol = OL + (size_t)node * F + halfLane * 8;
            *(ushort4*)oh = h0; *(ushort4*)(oh + 4) = h1;
            *(ushort4*)ol = l0; *(ushort4*)(ol + 4) = l1;
        } else {
            float* o = OUT + (size_t)node * F + halfLane * 8;
            float4 r0, r1;
            r0.x = vals[0]; r0.y = vals[1]; r0.z = vals[2]; r0.w = vals[3];
            r1.x = vals[4]; r1.y = vals[5]; r1.z = vals[6]; r1.w = vals[7];
            *(float4*)o = r0;
            *(float4*)(o + 4) = r1;
        }
    }
}

// ---------- launch ----------
extern "C" void kernel_launch(void* const* d_in, const int* in_sizes, int n_in,
                              void* d_out, int out_size, void* d_ws, size_t ws_size,
                              hipStream_t stream)
{
    const int N = N_NODES, E = N_EDGES;

    const float* x   = (const float*)d_in[0];
    const int*   und = (const int*)d_in[1];
    const int*   dir = (const int*)d_in[2];
    const float* W1  = (const float*)d_in[3];
    const float* as1 = (const float*)d_in[4];
    const float* ad1 = (const float*)d_in[5];
    const float* b1  = (const float*)d_in[6];
    const float* W2  = (const float*)d_in[7];
    const float* as2 = (const float*)d_in[8];
    const float* ad2 = (const float*)d_in[9];
    const float* b2  = (const float*)d_in[10];

    char* p = (char*)d_ws;
    auto alloc = [&](size_t bytes) {
        char* r = p;
        p += (bytes + 255) & ~(size_t)255;
        return r;
    };
    unsigned short* xl1 = (unsigned short*)alloc((size_t)N * 128 * 2);  // bf16
    unsigned short* hh  = (unsigned short*)alloc((size_t)N * 128 * 2);  // h hi
    unsigned short* hl  = (unsigned short*)alloc((size_t)N * 128 * 2);  // h lo
    unsigned short* xl2 = (unsigned short*)alloc((size_t)N * 256 * 2);  // bf16
    float* a_src   = (float*)alloc((size_t)N * 2 * 4);
    float* a_dst   = (float*)alloc((size_t)N * 2 * 4);
    int*   cnts    = (int*)alloc(((size_t)2 * N + 2 * NBUCK) * 4);
    int*   ss1     = (int*)alloc((size_t)N * CAP * 4);
    int*   ss2     = (int*)alloc((size_t)N * CAP * 4);
    unsigned short* w1ht = (unsigned short*)alloc((size_t)128 * 64 * 2);
    unsigned short* w1lt = (unsigned short*)alloc((size_t)128 * 64 * 2);
    unsigned short* w2ht = (unsigned short*)alloc((size_t)256 * 128 * 2);
    unsigned short* w2lt = (unsigned short*)alloc((size_t)256 * 128 * 2);
    int* cnt1 = cnts, * cnt2 = cnts + N, * gcur = cnts + 2 * N;

    // staging for the radix pass aliases xl2 (9.0MB < 25.6MB; xl2 written
    // later by gemm2, after place_kernel completed).
    unsigned int* stage = (unsigned int*)xl2;
    // x split (hi|lo, 6.4MB each) scratches in d_out (51.2MB), which is
    // fully overwritten by the final aggregate afterwards.
    unsigned short* x1h = (unsigned short*)d_out;
    unsigned short* x1l = (unsigned short*)d_out + (size_t)N * 64;

    const int WB = (N * 64 + 255) / 256;     // wave-per-node blocks

    // ===== 2-level LDS counting-sort edge binning, both layers =====
    hipMemsetAsync(gcur, 0, (size_t)2 * NBUCK * 4, stream);
    bucket_kernel<<<2 * 196, 256, 0, stream>>>(und, dir, E, gcur, stage);
    place_kernel<<<2 * NBUCK, 256, 0, stream>>>(stage, gcur, cnt1, cnt2, ss1, ss2);

    // ===== prep: split-bf16 operands =====
    splitWT_kernel<<<(128 * 64 + 255) / 256, 256, 0, stream>>>(W1, w1ht, w1lt, 64, 128);
    splitWT_kernel<<<(256 * 128 + 255) / 256, 256, 0, stream>>>(W2, w2ht, w2lt, 128, 256);
    splitX_kernel<<<(N * 64 / 4 + 255) / 256, 256, 0, stream>>>(x, x1h, x1l, N * 64 / 4);

    // ===== Layer 1: K=64, N=128 (H=2, Fh=64), undirected edges =====
    mfma_gemm_kernel<64, 128, 1><<<768, 512, 0, stream>>>(x1h, x1l, w1ht, w1lt, xl1, N);
    att_kernel<128><<<WB, 256, 0, stream>>>(xl1, as1, ad1, a_src, a_dst, N);
    aggregate_kernel<128, 4, true><<<WB, 256, 0, stream>>>(
        xl1, a_src, a_dst, cnt1, ss1, b1, nullptr, hh, hl, N);

    // ===== Layer 2: K=128, N=256 (H=2, Fh=128), directed edges =====
    mfma_gemm_kernel<128, 256, 2><<<384, 512, 0, stream>>>(hh, hl, w2ht, w2lt, xl2, N);
    att_kernel<256><<<WB, 256, 0, stream>>>(xl2, as2, ad2, a_src, a_dst, N);
    aggregate_kernel<256, 2, false><<<WB, 256, 0, stream>>>(
        xl2, a_src, a_dst, cnt2, ss2, b2, (float*)d_out, nullptr, nullptr, N);
}